// Round 9
// baseline (240.423 us; speedup 1.0000x reference)
//
#include <hip/hip_runtime.h>
#include <stdint.h>
#include <math.h>

#define N_ANCH   1000000
#define N4       (N_ANCH / 4)          // 250000 uint4 key packs
#define NBLK4    ((N4 + 1023) / 1024)  // 245 blocks (1024-thr kernels)
#define NBLK256  ((N4 + 255) / 256)    // 977 blocks (256-thr kernels)
#define PRE_K    6000
#define POST_K   1000
#define WORDS    94            // ceil(6000/64) -> 6016 bit columns
#define ROWS     6016          // WORDS*64
#define W_IMG    1333.0f
#define H_IMG    800.0f

#define NS       7168          // candidate capacity (112 blocks of 64)
#define RBLK     112           // rank blocks

#define NMS_WAVES 8
#define RPW       8            // rows per wave in the k_nms fold (64/NMS_WAVES)

// ws layout (bytes)
#define OFF_KEYS   0x000000u   // u32[1e6] = 4 MiB
#define OFF_HIST1  0x400000u   // u32[4096] global coarse hist (16 KiB)
#define OFF_HIST2  0x404000u   // u32[256]  global refine hist (1 KiB)
#define OFF_CTRL   0x410000u   // [0]=count [1]=T20 [2]=coarse c [3]=base
#define OFF_CAND   0x410100u   // u64[NS] 56 KiB
#define OFF_BOXES  0x41F000u   // float4[6016]
#define OFF_VALID  0x437000u   // u32[6016]
#define OFF_MASK   0x440000u   // u64[6016*94] row-major: mask[row*WORDS + w]

__device__ __forceinline__ float ref_exp(float v) {
  return (float)exp((double)v);   // correctly-rounded f32 exp via double
}

__device__ __forceinline__ void decode_box(float ax, float ay, float az, float aw,
                                           float dx, float dy, float dz, float dw,
                                           float& x1, float& y1, float& x2, float& y2,
                                           bool& valid) {
  // bit-exact replica of reference fp32 op order (no FMA contraction)
  float wa = __fsub_rn(az, ax);
  float ha = __fsub_rn(aw, ay);
  float xa = __fadd_rn(ax, __fmul_rn(0.5f, wa));
  float ya = __fadd_rn(ay, __fmul_rn(0.5f, ha));
  float x  = __fadd_rn(__fmul_rn(dx, wa), xa);
  float y  = __fadd_rn(__fmul_rn(dy, ha), ya);
  float w  = __fmul_rn(ref_exp(dz), wa);
  float h  = __fmul_rn(ref_exp(dw), ha);
  float hw = __fmul_rn(0.5f, w);
  float hh = __fmul_rn(0.5f, h);
  x1 = fminf(fmaxf(__fsub_rn(x, hw), 0.0f), W_IMG - 1.0f);
  y1 = fminf(fmaxf(__fsub_rn(y, hh), 0.0f), H_IMG - 1.0f);
  x2 = fminf(fmaxf(__fadd_rn(x, hw), 0.0f), W_IMG - 1.0f);
  y2 = fminf(fmaxf(__fadd_rn(y, hh), 0.0f), H_IMG - 1.0f);
  valid = (__fsub_rn(x2, x1) >= 16.0f) && (__fsub_rn(y2, y1) >= 16.0f);
}

__device__ __forceinline__ uint32_t wave_iscan(uint32_t x, int lane) {
  #pragma unroll
  for (int off = 1; off < 64; off <<= 1) {
    uint32_t u = __shfl_up(x, off, 64);
    if (lane >= off) x += u;
  }
  return x;
}

// wave-uniform 64-bit broadcast via v_readlane
__device__ __forceinline__ uint64_t bcast64(uint64_t v, int lane) {
  uint32_t lo = (uint32_t)__builtin_amdgcn_readlane((int)(uint32_t)v, lane);
  uint32_t hi = (uint32_t)__builtin_amdgcn_readlane((int)(uint32_t)(v >> 32), lane);
  return ((uint64_t)hi << 32) | lo;
}

// ---- K0: PURE streaming decode -> logit-bit key. No LDS, no atomics, no barriers. ----
__global__ void __launch_bounds__(256) k_decode(const float4* __restrict__ anchors,
                                                const float4* __restrict__ deltas,
                                                const float*  __restrict__ logits,
                                                uint32_t* __restrict__ keys) {
  int i = blockIdx.x * 256 + threadIdx.x;
  if (i >= N_ANCH) return;
  float4 a = anchors[i];
  float4 d = deltas[i];
  // fast f32 decode (filter only; exact op order irrelevant under margin)
  float wa = a.z - a.x, ha = a.w - a.y;
  float xa = a.x + 0.5f * wa, ya = a.y + 0.5f * ha;
  float x = d.x * wa + xa, y = d.y * ha + ya;
  float w = __expf(d.z) * wa, h = __expf(d.w) * ha;
  float fx1 = fminf(fmaxf(x - 0.5f * w, 0.0f), W_IMG - 1.0f);
  float fx2 = fminf(fmaxf(x + 0.5f * w, 0.0f), W_IMG - 1.0f);
  float fy1 = fminf(fmaxf(y - 0.5f * h, 0.0f), H_IMG - 1.0f);
  float fy2 = fminf(fmaxf(y + 0.5f * h, 0.0f), H_IMG - 1.0f);
  float X = fx2 - fx1, Y = fy2 - fy1;
  bool valid = (X >= 16.0f) && (Y >= 16.0f);
  if (fabsf(X - 16.0f) < 0.02f || fabsf(Y - 16.0f) < 0.02f) {
    float ex1, ey1, ex2, ey2; bool vv;      // borderline: exact f64 recheck (rare)
    decode_box(a.x, a.y, a.z, a.w, d.x, d.y, d.z, d.w, ex1, ey1, ex2, ey2, vv);
    valid = vv;
  }
  uint32_t u = __float_as_uint(logits[i]);
  uint32_t o = (u & 0x80000000u) ? ~u : (u | 0x80000000u);  // ascending in logit
  keys[i] = valid ? ~o : 0xFFFFFFFFu;                       // ascending key = descending logit
}

// ---- K1: 12-bit coarse hist over keys (uint4 loads, one pack/thread). ----
__global__ void __launch_bounds__(1024) k_histA(const uint4* __restrict__ keys4,
                                                uint32_t* __restrict__ hist1) {
  __shared__ uint32_t lh[4096];
  int tid = threadIdx.x, lane = tid & 63;
  for (int b = tid; b < 4096; b += 1024) lh[b] = 0u;
  __syncthreads();
  int i4 = blockIdx.x * 1024 + tid;
  uint32_t invc = 0;
  if (i4 < N4) {
    uint4 kk = keys4[i4];
    uint32_t ks[4] = { kk.x, kk.y, kk.z, kk.w };
    #pragma unroll
    for (int e = 0; e < 4; e++) {
      if (ks[e] != 0xFFFFFFFFu) atomicAdd(&lh[ks[e] >> 20], 1u);
      else invc++;
    }
  }
  #pragma unroll
  for (int off = 32; off > 0; off >>= 1) invc += __shfl_down(invc, off, 64);
  if (lane == 0 && invc) atomicAdd(&lh[4095], invc);
  __syncthreads();
  for (int b = tid; b < 4096; b += 1024) {     // sparse flush
    uint32_t cv = lh[b];
    if (cv) atomicAdd(&hist1[b], cv);
  }
}

// ---- K1b: coarse cut, ONE tiny block. Writes ctrl[2]=c, ctrl[3]=base.
// Kernel boundary publishes ctrl (no fences needed).
__global__ void __launch_bounds__(1024) k_cut1(const uint32_t* __restrict__ hist1,
                                               uint32_t* __restrict__ ctrl) {
  __shared__ uint32_t part[1024];
  int t = threadIdx.x;
  uint4 s4 = ((const uint4*)hist1)[t];       // thread t owns bins 4t..4t+3
  uint32_t tot = s4.x + s4.y + s4.z + s4.w;
  part[t] = tot;
  __syncthreads();
  uint32_t inc = tot;
  for (int off = 1; off < 1024; off <<= 1) {
    uint32_t u = (t >= off) ? part[t - off] : 0u;
    __syncthreads();
    inc += u;
    part[t] = inc;
    __syncthreads();
  }
  uint32_t ex = inc - tot;
  if (ex < PRE_K && inc >= PRE_K) {
    uint32_t run = ex;
    uint32_t binv[4] = { s4.x, s4.y, s4.z, s4.w };
    for (int b = 0; b < 4; b++) {
      if (run + binv[b] >= PRE_K) { ctrl[2] = 4 * t + b; ctrl[3] = run; break; }
      run += binv[b];
    }
  }
  if (t == 1023 && inc < PRE_K) { ctrl[2] = 4095u; ctrl[3] = inc; }  // take everything
}

// ---- K2: refine next 8 bits within coarse bin c (pure streaming, 256 thr) ----
__global__ void __launch_bounds__(256) k_hist2(const uint4* __restrict__ keys4,
                                               const uint32_t* __restrict__ ctrl,
                                               uint32_t* __restrict__ hist2) {
  __shared__ uint32_t lh[256];
  int tid = threadIdx.x;
  lh[tid] = 0u;
  __syncthreads();
  uint32_t c = ctrl[2];
  int i4 = blockIdx.x * 256 + tid;
  if (i4 < N4) {
    uint4 kk = keys4[i4];
    uint32_t ks[4] = { kk.x, kk.y, kk.z, kk.w };
    #pragma unroll
    for (int e = 0; e < 4; e++)
      if ((ks[e] >> 20) == c) atomicAdd(&lh[(ks[e] >> 12) & 0xFFu], 1u);
  }
  __syncthreads();
  uint32_t v = lh[tid];
  if (v) atomicAdd(&hist2[tid], v);    // most blocks: zero atomics
}

// ---- K2b: sub-bin cut, ONE wave. Writes ctrl[1]=T (20-bit threshold). ----
__global__ void __launch_bounds__(64) k_cut2(const uint32_t* __restrict__ hist2,
                                             uint32_t* __restrict__ ctrl) {
  int lane = threadIdx.x;
  uint32_t c = ctrl[2], base = ctrl[3];
  const uint32_t* p = hist2 + 4 * lane;
  uint32_t b0 = p[0], b1 = p[1], b2 = p[2], b3 = p[3];
  uint32_t tot = b0 + b1 + b2 + b3;
  uint32_t inc = wave_iscan(tot, lane);
  uint32_t ex = inc - tot;
  bool found = false;
  if (base + ex < PRE_K && base + inc >= PRE_K) {
    uint32_t run = base + ex;
    uint32_t binv[4] = { b0, b1, b2, b3 };
    for (int b = 0; b < 4; b++) {
      if (run + binv[b] >= PRE_K) { ctrl[1] = (c << 8) | (uint32_t)(4 * lane + b); found = true; break; }
      run += binv[b];
    }
  }
  uint64_t fb = __ballot(found);
  if (lane == 0 && fb == 0ull) ctrl[1] = 0xFFFFFu;   // take everything
}

// ---- K3: compact candidates (key prefix <= T) + exact-sigmoid re-key ----
// Block-aggregated: ONE global atomic per block. cand order nondeterministic;
// fine, k_rank ranks by VALUE. ctrl passed non-restrict (cnt aliases ctrl[0]).
__global__ void __launch_bounds__(256) k_compact(const uint4* __restrict__ keys4,
                                                 const float* __restrict__ logits,
                                                 uint32_t* ctrl,
                                                 uint64_t* __restrict__ cand) {
  __shared__ uint32_t wcnt[4];
  __shared__ uint32_t bbase_s;
  int tid = threadIdx.x, lane = tid & 63, wv = tid >> 6;
  uint32_t T = ctrl[1];
  int i4 = blockIdx.x * 256 + tid;
  uint4 kk = make_uint4(~0u, ~0u, ~0u, ~0u);
  if (i4 < N4) kk = keys4[i4];
  uint32_t ks[4] = { kk.x, kk.y, kk.z, kk.w };
  bool pass[4]; uint64_t m[4];
  uint32_t tot = 0;
  #pragma unroll
  for (int e = 0; e < 4; e++) {
    pass[e] = (i4 < N4) && ((ks[e] >> 12) <= T);
    m[e] = __ballot(pass[e]);
    tot += (uint32_t)__popcll((unsigned long long)m[e]);
  }
  if (lane == 0) wcnt[wv] = tot;
  __syncthreads();
  if (tid == 0) {
    uint32_t bt = wcnt[0] + wcnt[1] + wcnt[2] + wcnt[3];
    bbase_s = bt ? atomicAdd(&ctrl[0], bt) : 0u;
  }
  __syncthreads();
  uint32_t wb = bbase_s;
  for (int w2 = 0; w2 < wv; w2++) wb += wcnt[w2];      // wave offset in block
  uint64_t lmask = (1ull << lane) - 1ull;
  #pragma unroll
  for (int e = 0; e < 4; e++) {
    if (pass[e]) {
      int i = 4 * i4 + e;
      uint32_t skey;
      if (ks[e] == 0xFFFFFFFFu) {
        skey = 0xFF800000u;                       // invalid -> -inf key
      } else {
        double xd = (double)logits[i];
        float s = (float)(1.0 / (1.0 + exp(-xd)));
        skey = 0x7FFFFFFFu & ~__float_as_uint(s); // descending-score -> ascending key
      }
      uint32_t p = wb + (uint32_t)__popcll((unsigned long long)(m[e] & lmask));
      if (p < NS) cand[p] = ((uint64_t)skey << 20) | (uint32_t)i;  // 52-bit packed
    }
    wb += (uint32_t)__popcll((unsigned long long)m[e]);
  }
}

// ---- K4: rank-by-count + gather/decode ----
// key64 all DISTINCT (idx embedded) -> rank is a bijection onto [0,M) equal to
// reference order (score desc, idx asc). 112 blocks x 4 waves.
__global__ void __launch_bounds__(256) k_rank(
    const uint32_t* __restrict__ ctrl,
    const uint64_t* __restrict__ cand,
    const float4* __restrict__ anchors,
    const float4* __restrict__ deltas,
    float4* __restrict__ boxes,
    uint32_t* __restrict__ valid) {
  __shared__ uint32_t part[4][64];
  int tid = threadIdx.x;
  int wv = tid >> 6, lane = tid & 63;
  int i = blockIdx.x * 64 + lane;            // own candidate slot (same for all 4 waves)
  uint32_t M = ctrl[0]; if (M > NS) M = NS;
  uint64_t myk = (i < (int)M) ? cand[i] : ~0ull;
  uint32_t cnt = 0;
  const int QUART = NS / 4;                  // 1792
  int jbase = wv * QUART;
  for (int s = 0; s < QUART / 64; s++) {     // 28 coalesced strips
    int j = jbase + s * 64 + lane;
    uint64_t c = (j < (int)M) ? cand[j] : ~0ull;   // sentinel: contributes 0
    #pragma unroll
    for (int s2 = 0; s2 < 64; s2++) {
      uint64_t kb = bcast64(c, s2);
      cnt += (kb < myk) ? 1u : 0u;
    }
  }
  part[wv][lane] = cnt;
  __syncthreads();
  if (wv != 0) return;
  uint32_t rank = part[0][lane] + part[1][lane] + part[2][lane] + part[3][lane];
  if (i < (int)M && rank < PRE_K) {
    uint32_t skey = (uint32_t)(myk >> 20);
    uint32_t idx  = (uint32_t)(myk & 0xFFFFFu);
    if (skey >= 0xFF800000u) {               // invalid candidate (take-everything case)
      boxes[rank] = make_float4(0.f, 0.f, 0.f, 0.f);
      valid[rank] = 0u;
    } else {
      float4 a = anchors[idx];
      float4 d = deltas[idx];
      float x1, y1, x2, y2; bool vv;
      decode_box(a.x, a.y, a.z, a.w, d.x, d.y, d.z, d.w, x1, y1, x2, y2, vv);
      boxes[rank] = make_float4(x1, y1, x2, y2);
      valid[rank] = 1u;
    }
  }
  // zero-fill all slots never touched by a rank-writer (bijection => no race)
  if ((i >= (int)M || i >= PRE_K) && i < ROWS) {
    boxes[i] = make_float4(0.f, 0.f, 0.f, 0.f);
    valid[i] = 0u;
  }
}

// ---- K5: IoU bitmask matrix, row-major mask[row*WORDS + w] ----
__global__ void __launch_bounds__(64) k_iou(const float4* __restrict__ boxes,
                                            uint64_t* __restrict__ mask) {
  int by = blockIdx.y, bx = blockIdx.x;
  if (bx < by) return;               // only words w >= row's group are ever read
  __shared__ float4 cb[64];
  int t = threadIdx.x;
  cb[t] = boxes[bx * 64 + t];
  __syncthreads();
  int i = by * 64 + t;
  float4 b = boxes[i];
  float ax1 = b.x, ay1 = b.y, ax2 = b.z, ay2 = b.w;
  float areaA = __fmul_rn(__fsub_rn(ax2, ax1), __fsub_rn(ay2, ay1));
  uint64_t bits = 0;
  for (int c = 0; c < 64; c++) {
    float4 o = cb[c];
    float areaB = __fmul_rn(__fsub_rn(o.z, o.x), __fsub_rn(o.w, o.y));
    float ix1 = fmaxf(ax1, o.x), iy1 = fmaxf(ay1, o.y);
    float ix2 = fminf(ax2, o.z), iy2 = fminf(ay2, o.w);
    float iw = fmaxf(__fsub_rn(ix2, ix1), 0.0f);
    float ih = fmaxf(__fsub_rn(iy2, iy1), 0.0f);
    float inter = __fmul_rn(iw, ih);
    float uni = __fsub_rn(__fadd_rn(areaA, areaB), inter);
    bool sup = (uni > 0.0f) && (__fdiv_rn(inter, uni) > 0.7f);
    bits |= ((uint64_t)sup) << c;
  }
  mask[(size_t)i * WORDS + bx] = bits;
}

// ---- K6: sequential NMS scan — 8-wave cooperative, pinned load batch ----
// v4: round-8 counters (VGPR_Count=64 < the 64 data regs + overhead needed)
// showed the compiler SANK the row loads into the fold loop -> 16 serialized
// load->wait->use chains (~8K cy/group, matches 59.5us). Fix:
//  (a) 8 waves x 8 rows: halves the per-lane batch, 2 waves/SIMD overlap drains;
//  (b) empty inline-asm "+v" pin on the batch after the chain: forces all 16
//      loads issued back-to-back with ONE vmcnt drain (not 16), off the
//      critical path of the SALU decision chain.
// Expected signature: VGPR_Count ~80-110, dur ~10us.
__global__ void __launch_bounds__(512, 1) k_nms(const uint64_t* __restrict__ mask,
                                                const float4* __restrict__ boxes,
                                                const uint32_t* __restrict__ valid,
                                                float* __restrict__ out) {
  __shared__ uint32_t list[1088];          // kept rows in scan order
  __shared__ uint64_t remS[2][NMS_WAVES];  // double-buffered cross-wave word exchange
  int tid = threadIdx.x;
  int lane = tid & 63, wv = tid >> 6;
  int wp = (2 * lane < WORDS) ? 2 * lane : 0;  // word pair owned (lanes 47..63 clamped, never read)
  uint64_t rA = 0, rB = 0;                 // THIS WAVE's partial removed words 2*lane, 2*lane+1
  int cnt = 0;
  if (tid < 2 * NMS_WAVES) ((uint64_t*)remS)[tid] = 0ull;
  uint64_t colv = mask[(size_t)lane * WORDS + 0];     // group-0 diag (all waves redundant)
  uint32_t vf = valid[lane];
  __syncthreads();
  for (int g = 0; g < WORDS; g++) {
    int base = g * 64;
    // ---- issue this wave's 8-row loads; pinned + drained at the fold below ----
    uint64_t vA[RPW], vB[RPW];
    #pragma unroll
    for (int k = 0; k < RPW; k++) {
      ulonglong2 t2 = *(const ulonglong2*)(mask + (size_t)(base + wv * RPW + k) * WORDS + wp);
      vA[k] = t2.x; vB[k] = t2.y;
    }
    uint64_t colv_c = colv;
    uint32_t vf_c = vf;
    if (g + 1 < WORDS) {                              // prefetch next diag + valid
      colv = mask[(size_t)(base + 64 + lane) * WORDS + (g + 1)];
      vf = valid[base + 64 + lane];
    }
    // cur = OR of the waves' partial removed word g (published last iter)
    uint64_t cur = 0;
    #pragma unroll
    for (int q = 0; q < NMS_WAVES; q++) cur |= remS[g & 1][q];
    uint64_t vmask = __ballot(vf_c != 0u);
    uint64_t alive = vmask & ~cur;
    // ---- branch-free decision chain: replicated in all waves ----
    uint64_t kept = 0;
    #pragma unroll
    for (int r = 0; r < 64; r++) {
      uint64_t mr = bcast64(colv_c, r);
      uint64_t take = (alive >> r) & 1ull;
      kept |= take << r;
      alive &= ~(take ? mr : 0ull);
    }
    // ---- record kept rows (wave 0 only; kept identical in all waves) ----
    if (wv == 0) {
      uint32_t below = (uint32_t)__popcll((unsigned long long)(kept & ((1ull << lane) - 1ull)));
      if ((kept >> lane) & 1ull) {
        uint32_t pos = (uint32_t)cnt + below;
        if (pos < 1088u) list[pos] = (uint32_t)(base + lane);
      }
    }
    cnt += (int)__popcll((unsigned long long)kept);   // uniform across waves
    if (cnt >= POST_K) break;                         // all waves break together
    if (g + 1 >= WORDS) break;
    // ---- pin: all 16 loads must be materialized HERE (one batched drain) ----
    asm volatile("" : "+v"(vA[0]), "+v"(vA[1]), "+v"(vA[2]), "+v"(vA[3]),
                      "+v"(vA[4]), "+v"(vA[5]), "+v"(vA[6]), "+v"(vA[7]),
                      "+v"(vB[0]), "+v"(vB[1]), "+v"(vB[2]), "+v"(vB[3]),
                      "+v"(vB[4]), "+v"(vB[5]), "+v"(vB[6]), "+v"(vB[7]));
    // ---- fold this wave's 8 rows ----
    uint64_t accA = 0, accB = 0;
    #pragma unroll
    for (int k = 0; k < RPW; k++) {
      uint64_t s = 0ull - ((kept >> (wv * RPW + k)) & 1ull);
      accA |= vA[k] & s;
      accB |= vB[k] & s;
    }
    rA |= accA;                                       // stale low words never re-read
    rB |= accB;
    // ---- publish partial removed word g+1 into the other buffer ----
    int nw = g + 1;
    if (lane == (nw >> 1)) remS[nw & 1][wv] = (nw & 1) ? rB : rA;
    __syncthreads();                                  // one barrier per group
  }
  __syncthreads();
  float4* outv = (float4*)out;
  for (int k = tid; k < POST_K; k += 512)
    outv[k] = (k < cnt) ? boxes[list[k]] : make_float4(0.f, 0.f, 0.f, 0.f);
}

extern "C" void kernel_launch(void* const* d_in, const int* in_sizes, int n_in,
                              void* d_out, int out_size, void* d_ws, size_t ws_size,
                              hipStream_t stream) {
  const float4* anchors = (const float4*)d_in[1];
  const float4* deltas  = (const float4*)d_in[2];
  const float*  logits  = (const float*)d_in[3];
  char* w = (char*)d_ws;
  uint32_t* keys  = (uint32_t*)(w + OFF_KEYS);
  uint32_t* hist1 = (uint32_t*)(w + OFF_HIST1);
  uint32_t* hist2 = (uint32_t*)(w + OFF_HIST2);
  uint32_t* ctrl  = (uint32_t*)(w + OFF_CTRL);
  uint64_t* cand  = (uint64_t*)(w + OFF_CAND);
  float4*   boxes = (float4*)(w + OFF_BOXES);
  uint32_t* valid = (uint32_t*)(w + OFF_VALID);
  uint64_t* mask  = (uint64_t*)(w + OFF_MASK);
  float*    out   = (float*)d_out;

  hipMemsetAsync(w + OFF_HIST1, 0, 0x4400, stream);  // hist1 (16K) + hist2 (1K)
  hipMemsetAsync(w + OFF_CTRL, 0, 256, stream);      // counters only

  k_decode<<<(N_ANCH + 255) / 256, 256, 0, stream>>>(anchors, deltas, logits, keys);
  k_histA<<<NBLK4, 1024, 0, stream>>>((const uint4*)keys, hist1);
  k_cut1<<<1, 1024, 0, stream>>>(hist1, ctrl);
  k_hist2<<<NBLK256, 256, 0, stream>>>((const uint4*)keys, ctrl, hist2);
  k_cut2<<<1, 64, 0, stream>>>(hist2, ctrl);
  k_compact<<<NBLK256, 256, 0, stream>>>((const uint4*)keys, logits, ctrl, cand);
  k_rank<<<RBLK, 256, 0, stream>>>(ctrl, cand, anchors, deltas, boxes, valid);
  k_iou<<<dim3(WORDS, WORDS), 64, 0, stream>>>(boxes, mask);
  k_nms<<<1, 64 * NMS_WAVES, 0, stream>>>(mask, boxes, valid, out);
}

// Round 10
// 238.450 us; speedup vs baseline: 1.0083x; 1.0083x over previous
//
#include <hip/hip_runtime.h>
#include <stdint.h>
#include <math.h>

#define N_ANCH   1000000
#define N4       (N_ANCH / 4)          // 250000 uint4 key packs
#define NBLK4    ((N4 + 1023) / 1024)  // 245 blocks (1024-thr kernels)
#define NBLK256  ((N4 + 255) / 256)    // 977 blocks (256-thr kernels)
#define PRE_K    6000
#define POST_K   1000
#define WORDS    94            // ceil(6000/64) -> 6016 bit columns
#define ROWS     6016          // WORDS*64
#define W_IMG    1333.0f
#define H_IMG    800.0f

#define NS       7168          // candidate capacity (112 blocks of 64)
#define RBLK     112           // rank blocks

#define OLDK     16            // old-kept gather batch: 16*64 >= 999+63 rows

// ws layout (bytes)
#define OFF_KEYS   0x000000u   // u32[1e6] = 4 MiB
#define OFF_HIST1  0x400000u   // u32[4096] global coarse hist (16 KiB)
#define OFF_HIST2  0x404000u   // u32[256]  global refine hist (1 KiB)
#define OFF_CTRL   0x410000u   // [0]=count [1]=T20 [2]=coarse c [3]=base
#define OFF_CAND   0x410100u   // u64[NS] 56 KiB
#define OFF_BOXES  0x41F000u   // float4[6016]
#define OFF_VALID  0x437000u   // u32[6016]
#define OFF_MASK   0x440000u   // u64[6016*94] row-major: mask[row*WORDS + w]

__device__ __forceinline__ float ref_exp(float v) {
  return (float)exp((double)v);   // correctly-rounded f32 exp via double
}

__device__ __forceinline__ void decode_box(float ax, float ay, float az, float aw,
                                           float dx, float dy, float dz, float dw,
                                           float& x1, float& y1, float& x2, float& y2,
                                           bool& valid) {
  // bit-exact replica of reference fp32 op order (no FMA contraction)
  float wa = __fsub_rn(az, ax);
  float ha = __fsub_rn(aw, ay);
  float xa = __fadd_rn(ax, __fmul_rn(0.5f, wa));
  float ya = __fadd_rn(ay, __fmul_rn(0.5f, ha));
  float x  = __fadd_rn(__fmul_rn(dx, wa), xa);
  float y  = __fadd_rn(__fmul_rn(dy, ha), ya);
  float w  = __fmul_rn(ref_exp(dz), wa);
  float h  = __fmul_rn(ref_exp(dw), ha);
  float hw = __fmul_rn(0.5f, w);
  float hh = __fmul_rn(0.5f, h);
  x1 = fminf(fmaxf(__fsub_rn(x, hw), 0.0f), W_IMG - 1.0f);
  y1 = fminf(fmaxf(__fsub_rn(y, hh), 0.0f), H_IMG - 1.0f);
  x2 = fminf(fmaxf(__fadd_rn(x, hw), 0.0f), W_IMG - 1.0f);
  y2 = fminf(fmaxf(__fadd_rn(y, hh), 0.0f), H_IMG - 1.0f);
  valid = (__fsub_rn(x2, x1) >= 16.0f) && (__fsub_rn(y2, y1) >= 16.0f);
}

__device__ __forceinline__ uint32_t wave_iscan(uint32_t x, int lane) {
  #pragma unroll
  for (int off = 1; off < 64; off <<= 1) {
    uint32_t u = __shfl_up(x, off, 64);
    if (lane >= off) x += u;
  }
  return x;
}

// wave-uniform 64-bit broadcast via v_readlane
__device__ __forceinline__ uint64_t bcast64(uint64_t v, int lane) {
  uint32_t lo = (uint32_t)__builtin_amdgcn_readlane((int)(uint32_t)v, lane);
  uint32_t hi = (uint32_t)__builtin_amdgcn_readlane((int)(uint32_t)(v >> 32), lane);
  return ((uint64_t)hi << 32) | lo;
}

__device__ __forceinline__ uint64_t shflxor64(uint64_t v, int m) {
  uint32_t lo = (uint32_t)__shfl_xor((int)(uint32_t)v, m, 64);
  uint32_t hi = (uint32_t)__shfl_xor((int)(uint32_t)(v >> 32), m, 64);
  return ((uint64_t)hi << 32) | lo;
}

// ---- K0: PURE streaming decode -> logit-bit key. No LDS, no atomics, no barriers. ----
__global__ void __launch_bounds__(256) k_decode(const float4* __restrict__ anchors,
                                                const float4* __restrict__ deltas,
                                                const float*  __restrict__ logits,
                                                uint32_t* __restrict__ keys) {
  int i = blockIdx.x * 256 + threadIdx.x;
  if (i >= N_ANCH) return;
  float4 a = anchors[i];
  float4 d = deltas[i];
  // fast f32 decode (filter only; exact op order irrelevant under margin)
  float wa = a.z - a.x, ha = a.w - a.y;
  float xa = a.x + 0.5f * wa, ya = a.y + 0.5f * ha;
  float x = d.x * wa + xa, y = d.y * ha + ya;
  float w = __expf(d.z) * wa, h = __expf(d.w) * ha;
  float fx1 = fminf(fmaxf(x - 0.5f * w, 0.0f), W_IMG - 1.0f);
  float fx2 = fminf(fmaxf(x + 0.5f * w, 0.0f), W_IMG - 1.0f);
  float fy1 = fminf(fmaxf(y - 0.5f * h, 0.0f), H_IMG - 1.0f);
  float fy2 = fminf(fmaxf(y + 0.5f * h, 0.0f), H_IMG - 1.0f);
  float X = fx2 - fx1, Y = fy2 - fy1;
  bool valid = (X >= 16.0f) && (Y >= 16.0f);
  if (fabsf(X - 16.0f) < 0.02f || fabsf(Y - 16.0f) < 0.02f) {
    float ex1, ey1, ex2, ey2; bool vv;      // borderline: exact f64 recheck (rare)
    decode_box(a.x, a.y, a.z, a.w, d.x, d.y, d.z, d.w, ex1, ey1, ex2, ey2, vv);
    valid = vv;
  }
  uint32_t u = __float_as_uint(logits[i]);
  uint32_t o = (u & 0x80000000u) ? ~u : (u | 0x80000000u);  // ascending in logit
  keys[i] = valid ? ~o : 0xFFFFFFFFu;                       // ascending key = descending logit
}

// ---- K1: 12-bit coarse hist over keys (uint4 loads, one pack/thread). ----
__global__ void __launch_bounds__(1024) k_histA(const uint4* __restrict__ keys4,
                                                uint32_t* __restrict__ hist1) {
  __shared__ uint32_t lh[4096];
  int tid = threadIdx.x, lane = tid & 63;
  for (int b = tid; b < 4096; b += 1024) lh[b] = 0u;
  __syncthreads();
  int i4 = blockIdx.x * 1024 + tid;
  uint32_t invc = 0;
  if (i4 < N4) {
    uint4 kk = keys4[i4];
    uint32_t ks[4] = { kk.x, kk.y, kk.z, kk.w };
    #pragma unroll
    for (int e = 0; e < 4; e++) {
      if (ks[e] != 0xFFFFFFFFu) atomicAdd(&lh[ks[e] >> 20], 1u);
      else invc++;
    }
  }
  #pragma unroll
  for (int off = 32; off > 0; off >>= 1) invc += __shfl_down(invc, off, 64);
  if (lane == 0 && invc) atomicAdd(&lh[4095], invc);
  __syncthreads();
  for (int b = tid; b < 4096; b += 1024) {     // sparse flush
    uint32_t cv = lh[b];
    if (cv) atomicAdd(&hist1[b], cv);
  }
}

// ---- K1b: coarse cut, ONE tiny block. Writes ctrl[2]=c, ctrl[3]=base.
// Kernel boundary publishes ctrl (no fences needed).
__global__ void __launch_bounds__(1024) k_cut1(const uint32_t* __restrict__ hist1,
                                               uint32_t* __restrict__ ctrl) {
  __shared__ uint32_t part[1024];
  int t = threadIdx.x;
  uint4 s4 = ((const uint4*)hist1)[t];       // thread t owns bins 4t..4t+3
  uint32_t tot = s4.x + s4.y + s4.z + s4.w;
  part[t] = tot;
  __syncthreads();
  uint32_t inc = tot;
  for (int off = 1; off < 1024; off <<= 1) {
    uint32_t u = (t >= off) ? part[t - off] : 0u;
    __syncthreads();
    inc += u;
    part[t] = inc;
    __syncthreads();
  }
  uint32_t ex = inc - tot;
  if (ex < PRE_K && inc >= PRE_K) {
    uint32_t run = ex;
    uint32_t binv[4] = { s4.x, s4.y, s4.z, s4.w };
    for (int b = 0; b < 4; b++) {
      if (run + binv[b] >= PRE_K) { ctrl[2] = 4 * t + b; ctrl[3] = run; break; }
      run += binv[b];
    }
  }
  if (t == 1023 && inc < PRE_K) { ctrl[2] = 4095u; ctrl[3] = inc; }  // take everything
}

// ---- K2: refine next 8 bits within coarse bin c (pure streaming, 256 thr) ----
__global__ void __launch_bounds__(256) k_hist2(const uint4* __restrict__ keys4,
                                               const uint32_t* __restrict__ ctrl,
                                               uint32_t* __restrict__ hist2) {
  __shared__ uint32_t lh[256];
  int tid = threadIdx.x;
  lh[tid] = 0u;
  __syncthreads();
  uint32_t c = ctrl[2];
  int i4 = blockIdx.x * 256 + tid;
  if (i4 < N4) {
    uint4 kk = keys4[i4];
    uint32_t ks[4] = { kk.x, kk.y, kk.z, kk.w };
    #pragma unroll
    for (int e = 0; e < 4; e++)
      if ((ks[e] >> 20) == c) atomicAdd(&lh[(ks[e] >> 12) & 0xFFu], 1u);
  }
  __syncthreads();
  uint32_t v = lh[tid];
  if (v) atomicAdd(&hist2[tid], v);    // most blocks: zero atomics
}

// ---- K2b: sub-bin cut, ONE wave. Writes ctrl[1]=T (20-bit threshold). ----
__global__ void __launch_bounds__(64) k_cut2(const uint32_t* __restrict__ hist2,
                                             uint32_t* __restrict__ ctrl) {
  int lane = threadIdx.x;
  uint32_t c = ctrl[2], base = ctrl[3];
  const uint32_t* p = hist2 + 4 * lane;
  uint32_t b0 = p[0], b1 = p[1], b2 = p[2], b3 = p[3];
  uint32_t tot = b0 + b1 + b2 + b3;
  uint32_t inc = wave_iscan(tot, lane);
  uint32_t ex = inc - tot;
  bool found = false;
  if (base + ex < PRE_K && base + inc >= PRE_K) {
    uint32_t run = base + ex;
    uint32_t binv[4] = { b0, b1, b2, b3 };
    for (int b = 0; b < 4; b++) {
      if (run + binv[b] >= PRE_K) { ctrl[1] = (c << 8) | (uint32_t)(4 * lane + b); found = true; break; }
      run += binv[b];
    }
  }
  uint64_t fb = __ballot(found);
  if (lane == 0 && fb == 0ull) ctrl[1] = 0xFFFFFu;   // take everything
}

// ---- K3: compact candidates (key prefix <= T) + exact-sigmoid re-key ----
// Block-aggregated: ONE global atomic per block. cand order nondeterministic;
// fine, k_rank ranks by VALUE. ctrl passed non-restrict (cnt aliases ctrl[0]).
__global__ void __launch_bounds__(256) k_compact(const uint4* __restrict__ keys4,
                                                 const float* __restrict__ logits,
                                                 uint32_t* ctrl,
                                                 uint64_t* __restrict__ cand) {
  __shared__ uint32_t wcnt[4];
  __shared__ uint32_t bbase_s;
  int tid = threadIdx.x, lane = tid & 63, wv = tid >> 6;
  uint32_t T = ctrl[1];
  int i4 = blockIdx.x * 256 + tid;
  uint4 kk = make_uint4(~0u, ~0u, ~0u, ~0u);
  if (i4 < N4) kk = keys4[i4];
  uint32_t ks[4] = { kk.x, kk.y, kk.z, kk.w };
  bool pass[4]; uint64_t m[4];
  uint32_t tot = 0;
  #pragma unroll
  for (int e = 0; e < 4; e++) {
    pass[e] = (i4 < N4) && ((ks[e] >> 12) <= T);
    m[e] = __ballot(pass[e]);
    tot += (uint32_t)__popcll((unsigned long long)m[e]);
  }
  if (lane == 0) wcnt[wv] = tot;
  __syncthreads();
  if (tid == 0) {
    uint32_t bt = wcnt[0] + wcnt[1] + wcnt[2] + wcnt[3];
    bbase_s = bt ? atomicAdd(&ctrl[0], bt) : 0u;
  }
  __syncthreads();
  uint32_t wb = bbase_s;
  for (int w2 = 0; w2 < wv; w2++) wb += wcnt[w2];      // wave offset in block
  uint64_t lmask = (1ull << lane) - 1ull;
  #pragma unroll
  for (int e = 0; e < 4; e++) {
    if (pass[e]) {
      int i = 4 * i4 + e;
      uint32_t skey;
      if (ks[e] == 0xFFFFFFFFu) {
        skey = 0xFF800000u;                       // invalid -> -inf key
      } else {
        double xd = (double)logits[i];
        float s = (float)(1.0 / (1.0 + exp(-xd)));
        skey = 0x7FFFFFFFu & ~__float_as_uint(s); // descending-score -> ascending key
      }
      uint32_t p = wb + (uint32_t)__popcll((unsigned long long)(m[e] & lmask));
      if (p < NS) cand[p] = ((uint64_t)skey << 20) | (uint32_t)i;  // 52-bit packed
    }
    wb += (uint32_t)__popcll((unsigned long long)m[e]);
  }
}

// ---- K4: rank-by-count + gather/decode ----
// key64 all DISTINCT (idx embedded) -> rank is a bijection onto [0,M) equal to
// reference order (score desc, idx asc). 112 blocks x 4 waves.
__global__ void __launch_bounds__(256) k_rank(
    const uint32_t* __restrict__ ctrl,
    const uint64_t* __restrict__ cand,
    const float4* __restrict__ anchors,
    const float4* __restrict__ deltas,
    float4* __restrict__ boxes,
    uint32_t* __restrict__ valid) {
  __shared__ uint32_t part[4][64];
  int tid = threadIdx.x;
  int wv = tid >> 6, lane = tid & 63;
  int i = blockIdx.x * 64 + lane;            // own candidate slot (same for all 4 waves)
  uint32_t M = ctrl[0]; if (M > NS) M = NS;
  uint64_t myk = (i < (int)M) ? cand[i] : ~0ull;
  uint32_t cnt = 0;
  const int QUART = NS / 4;                  // 1792
  int jbase = wv * QUART;
  for (int s = 0; s < QUART / 64; s++) {     // 28 coalesced strips
    int j = jbase + s * 64 + lane;
    uint64_t c = (j < (int)M) ? cand[j] : ~0ull;   // sentinel: contributes 0
    #pragma unroll
    for (int s2 = 0; s2 < 64; s2++) {
      uint64_t kb = bcast64(c, s2);
      cnt += (kb < myk) ? 1u : 0u;
    }
  }
  part[wv][lane] = cnt;
  __syncthreads();
  if (wv != 0) return;
  uint32_t rank = part[0][lane] + part[1][lane] + part[2][lane] + part[3][lane];
  if (i < (int)M && rank < PRE_K) {
    uint32_t skey = (uint32_t)(myk >> 20);
    uint32_t idx  = (uint32_t)(myk & 0xFFFFFu);
    if (skey >= 0xFF800000u) {               // invalid candidate (take-everything case)
      boxes[rank] = make_float4(0.f, 0.f, 0.f, 0.f);
      valid[rank] = 0u;
    } else {
      float4 a = anchors[idx];
      float4 d = deltas[idx];
      float x1, y1, x2, y2; bool vv;
      decode_box(a.x, a.y, a.z, a.w, d.x, d.y, d.z, d.w, x1, y1, x2, y2, vv);
      boxes[rank] = make_float4(x1, y1, x2, y2);
      valid[rank] = 1u;
    }
  }
  // zero-fill all slots never touched by a rank-writer (bijection => no race)
  if ((i >= (int)M || i >= PRE_K) && i < ROWS) {
    boxes[i] = make_float4(0.f, 0.f, 0.f, 0.f);
    valid[i] = 0u;
  }
}

// ---- K5: IoU bitmask matrix, row-major mask[row*WORDS + w] ----
__global__ void __launch_bounds__(64) k_iou(const float4* __restrict__ boxes,
                                            uint64_t* __restrict__ mask) {
  int by = blockIdx.y, bx = blockIdx.x;
  if (bx < by) return;               // only words w >= row's group are ever read
  __shared__ float4 cb[64];
  int t = threadIdx.x;
  cb[t] = boxes[bx * 64 + t];
  __syncthreads();
  int i = by * 64 + t;
  float4 b = boxes[i];
  float ax1 = b.x, ay1 = b.y, ax2 = b.z, ay2 = b.w;
  float areaA = __fmul_rn(__fsub_rn(ax2, ax1), __fsub_rn(ay2, ay1));
  uint64_t bits = 0;
  for (int c = 0; c < 64; c++) {
    float4 o = cb[c];
    float areaB = __fmul_rn(__fsub_rn(o.z, o.x), __fsub_rn(o.w, o.y));
    float ix1 = fmaxf(ax1, o.x), iy1 = fmaxf(ay1, o.y);
    float ix2 = fminf(ax2, o.z), iy2 = fminf(ay2, o.w);
    float iw = fmaxf(__fsub_rn(ix2, ix1), 0.0f);
    float ih = fmaxf(__fsub_rn(iy2, iy1), 0.0f);
    float inter = __fmul_rn(iw, ih);
    float uni = __fsub_rn(__fadd_rn(areaA, areaB), inter);
    bool sup = (uni > 0.0f) && (__fdiv_rn(inter, uni) > 0.7f);
    bits |= ((uint64_t)sup) << c;
  }
  mask[(size_t)i * WORDS + bx] = bits;
}

// ---- K6: sequential NMS scan — single wave, LAZY column gather ----
// v5: rounds 7-9 showed ~60-70us regardless of fold/load scheduling -> the
// eager 94-word fold (48KB loads/group) + cross-wave exchange was never the
// right shape. Lazy reformulation: the scan only consumes removed[g], ONE
// word per group. Compute removed[g+1] on demand:
//   removed[g+1] = OR over kept rows r of mask[r][g+1]
//                = (select-OR of current group's 64 rows, 1 load/lane)
//                | (gather over list[] of previously-kept rows, <=16 loads/lane)
// All gathers are issued BEFORE the 64-step decision chain (~800cy) so their
// L2/L3 latency hides under it; asm pin prevents the compiler from sinking
// them. Single wave: no barriers, no LDS exchange, no removed-word state.
// Loads drop 48KB -> ~10KB per group.
__global__ void __launch_bounds__(64, 1) k_nms(const uint64_t* __restrict__ mask,
                                               const float4* __restrict__ boxes,
                                               const uint32_t* __restrict__ valid,
                                               float* __restrict__ out) {
  __shared__ uint32_t list[1088];     // kept rows in scan order (cnt < 1064)
  int lane = threadIdx.x;
  uint64_t lmask = (1ull << lane) - 1ull;
  int cnt = 0;
  uint64_t colv = mask[(size_t)lane * WORDS + 0];   // group-0 diagonal
  uint32_t vf = valid[lane];
  uint64_t cur = 0;                                 // removed[0] = 0
  for (int g = 0; g < WORDS; g++) {
    int base = g * 64;
    bool haveNext = (g + 1 < WORDS);
    // ---- issue gathers for removed[g+1] + next diag/valid (hidden under chain) ----
    uint64_t newv = 0, colv_n = 0, oldv[OLDK];
    uint32_t vf_n = 0, om = 0;
    if (haveNext) {
      newv   = mask[(size_t)(base + lane) * WORDS + (g + 1)];        // own row's col g+1
      colv_n = mask[(size_t)(base + 64 + lane) * WORDS + (g + 1)];   // next diag
      vf_n   = valid[base + 64 + lane];
      #pragma unroll
      for (int k = 0; k < OLDK; k++) {            // previously-kept rows' col g+1
        int t = 64 * k + lane;
        uint32_t row = (t < cnt) ? list[t] : 0u;  // clamped safe address
        om |= (t < cnt) ? (1u << k) : 0u;
        oldv[k] = mask[(size_t)row * WORDS + (g + 1)];
      }
    }
    // ---- branch-free 64-step decision chain (wave-uniform SALU) ----
    uint64_t vmask = __ballot(vf != 0u);
    uint64_t alive = vmask & ~cur;
    uint64_t kept = 0;
    #pragma unroll
    for (int r = 0; r < 64; r++) {
      uint64_t mr = bcast64(colv, r);
      uint64_t take = (alive >> r) & 1ull;
      kept |= take << r;
      alive &= ~(take ? mr : 0ull);
    }
    // ---- record kept rows (in-wave, no barrier) ----
    uint32_t below = (uint32_t)__popcll((unsigned long long)(kept & lmask));
    if ((kept >> lane) & 1ull) {
      uint32_t pos = (uint32_t)cnt + below;
      if (pos < 1088u) list[pos] = (uint32_t)(base + lane);
    }
    cnt += (int)__popcll((unsigned long long)kept);
    if (cnt >= POST_K || !haveNext) break;
    // ---- pin gather batch in VGPRs (defeat load sinking), then select-OR ----
    asm volatile("" : "+v"(newv),
                      "+v"(oldv[0]),  "+v"(oldv[1]),  "+v"(oldv[2]),  "+v"(oldv[3]),
                      "+v"(oldv[4]),  "+v"(oldv[5]),  "+v"(oldv[6]),  "+v"(oldv[7]),
                      "+v"(oldv[8]),  "+v"(oldv[9]),  "+v"(oldv[10]), "+v"(oldv[11]),
                      "+v"(oldv[12]), "+v"(oldv[13]), "+v"(oldv[14]), "+v"(oldv[15]));
    uint64_t acc = ((kept >> lane) & 1ull) ? newv : 0ull;
    #pragma unroll
    for (int k = 0; k < OLDK; k++)
      acc |= oldv[k] & (0ull - (uint64_t)((om >> k) & 1u));
    #pragma unroll
    for (int off = 1; off < 64; off <<= 1)        // wave-OR reduce
      acc |= shflxor64(acc, off);
    cur = bcast64(acc, 0);                        // wave-uniform removed[g+1]
    colv = colv_n; vf = vf_n;
  }
  __syncthreads();
  float4* outv = (float4*)out;
  for (int k = lane; k < POST_K; k += 64)
    outv[k] = (k < cnt) ? boxes[list[k]] : make_float4(0.f, 0.f, 0.f, 0.f);
}

extern "C" void kernel_launch(void* const* d_in, const int* in_sizes, int n_in,
                              void* d_out, int out_size, void* d_ws, size_t ws_size,
                              hipStream_t stream) {
  const float4* anchors = (const float4*)d_in[1];
  const float4* deltas  = (const float4*)d_in[2];
  const float*  logits  = (const float*)d_in[3];
  char* w = (char*)d_ws;
  uint32_t* keys  = (uint32_t*)(w + OFF_KEYS);
  uint32_t* hist1 = (uint32_t*)(w + OFF_HIST1);
  uint32_t* hist2 = (uint32_t*)(w + OFF_HIST2);
  uint32_t* ctrl  = (uint32_t*)(w + OFF_CTRL);
  uint64_t* cand  = (uint64_t*)(w + OFF_CAND);
  float4*   boxes = (float4*)(w + OFF_BOXES);
  uint32_t* valid = (uint32_t*)(w + OFF_VALID);
  uint64_t* mask  = (uint64_t*)(w + OFF_MASK);
  float*    out   = (float*)d_out;

  hipMemsetAsync(w + OFF_HIST1, 0, 0x4400, stream);  // hist1 (16K) + hist2 (1K)
  hipMemsetAsync(w + OFF_CTRL, 0, 256, stream);      // counters only

  k_decode<<<(N_ANCH + 255) / 256, 256, 0, stream>>>(anchors, deltas, logits, keys);
  k_histA<<<NBLK4, 1024, 0, stream>>>((const uint4*)keys, hist1);
  k_cut1<<<1, 1024, 0, stream>>>(hist1, ctrl);
  k_hist2<<<NBLK256, 256, 0, stream>>>((const uint4*)keys, ctrl, hist2);
  k_cut2<<<1, 64, 0, stream>>>(hist2, ctrl);
  k_compact<<<NBLK256, 256, 0, stream>>>((const uint4*)keys, logits, ctrl, cand);
  k_rank<<<RBLK, 256, 0, stream>>>(ctrl, cand, anchors, deltas, boxes, valid);
  k_iou<<<dim3(WORDS, WORDS), 64, 0, stream>>>(boxes, mask);
  k_nms<<<1, 64, 0, stream>>>(mask, boxes, valid, out);
}